// Round 19
// baseline (44.528 us; speedup 1.0000x reference)
//
#include <hip/hip_runtime.h>
#include <math.h>

#define N_NODES 8192
#define FDIM 256
#define DDIM 128
#define SLOPE 0.2f
#define MAXD 128      // unique neighbors kept/row; true max ~50, validated R5-R18
#define RSL 32        // slots per row per XCD replica (mean 4, 14-sigma safe)
#define NREP 8        // one replica per XCD

typedef __attribute__((ext_vector_type(8))) short bf16x8;
typedef __attribute__((ext_vector_type(4))) float f32x4;

__device__ __forceinline__ unsigned short f2bf(float f) {     // RNE fp32->bf16
    unsigned u = __float_as_uint(f);
    u += 0x7fffu + ((u >> 16) & 1u);
    return (unsigned short)(u >> 16);
}
__device__ __forceinline__ float bf2f(unsigned short h) {
    return __uint_as_float(((unsigned)h) << 16);
}

// ---------------- prep: zero replica counters + pack Ws into MFMA B fragments -------
__global__ __launch_bounds__(256) void prep_k(const float* __restrict__ Ws,
                                              unsigned short* __restrict__ Bphi,
                                              unsigned short* __restrict__ Bplo,
                                              unsigned* __restrict__ cnt8) {
    int b = blockIdx.x, t = threadIdx.x;
    int zi = b * 256 + t;                        // 65536 threads
    if (zi < NREP * N_NODES / 4) ((uint4*)cnt8)[zi] = make_uint4(0u, 0u, 0u, 0u);

    if (b >= 16) return;
    // B pack (validated R16-R18): frag (ct,ks): lane l elem e = Ws[ks*32+(l>>4)*8+e][ct*16+(l&15)]
    int tid = b * 256 + t;                       // < 4096
    int ct = tid >> 9, ks = (tid >> 6) & 7, l = tid & 63;
    int kbase = ks * 32 + (l >> 4) * 8;
    int col = ct * 16 + (l & 15);
    bf16x8 h, lo;
#pragma unroll
    for (int q = 0; q < 8; q++) {
        float v = Ws[(size_t)(kbase + q) * DDIM + col];
        unsigned short hq = f2bf(v);
        h[q] = (short)hq;
        lo[q] = (short)f2bf(v - bf2f(hq));
    }
    *(bf16x8*)(Bphi + (size_t)tid * 8) = h;
    *(bf16x8*)(Bplo + (size_t)tid * 8) = lo;
}

// ---------------- mega: MFMA gemm (bid<512) || XCD-local ELL build (bid>=512) -------
// build: replica = own XCD (s_getreg HW_REG_XCC_ID, m09-verified). All RMWs for
// replica k come only from XCD k -> TCC-local atomics, no cross-XCD coherence.
// Theory: the 19us build wall (R13/R15/R17, flavor-independent) is cross-XCD RMW
// serialization; locality should recover up to 8x.
__global__ __launch_bounds__(256) void mega_k(const int* __restrict__ edge, int E,
                                              const float* __restrict__ X,
                                              const unsigned short* __restrict__ Bphi,
                                              const unsigned short* __restrict__ Bplo,
                                              const float* __restrict__ a,
                                              unsigned short* __restrict__ WhB,
                                              float* __restrict__ s1,
                                              float* __restrict__ s2,
                                              unsigned* __restrict__ cnt8,
                                              unsigned* __restrict__ ell8) {
    __shared__ unsigned short Ah[16 * 264], Al[16 * 264];   // 16.5 KB
    __shared__ float ps1[64], ps2[64];
    int bid = blockIdx.x, t = threadIdx.x;

    if (bid >= 512) {                    // ---- build role: 1024 blocks, 256 edges ----
        unsigned xcd;
        asm volatile("s_getreg_b32 %0, hwreg(HW_REG_XCC_ID)" : "=s"(xcd));
        xcd &= 7u;
        int e = (bid - 512) * 256 + t;
        if (e < E) {
            int r = edge[e];             // edge_index[0][e] : softmax row
            int c = edge[E + e];         // edge_index[1][e] : neighbor
            size_t rowk = (size_t)xcd * N_NODES + (unsigned)r;
            unsigned slot = atomicAdd(&cnt8[rowk], 1u);
            if (slot < RSL) ell8[rowk * RSL + slot] = (unsigned)c;
        }
        return;
    }

    // ---- gemm role: 512 blocks (R16-R18 validated, 7.4us measured) ----
    int w = t >> 6, lane = t & 63, lr = lane & 15, kg = lane >> 4;
    int row0 = bid * 16;

    const float4* Xg = (const float4*)(X + (size_t)row0 * FDIM);
#pragma unroll
    for (int i = 0; i < 4; i++) {
        int lin = t + 256 * i;
        int r = lin >> 6, q = lin & 63;
        float4 v = Xg[r * 64 + q];
        ushort4 h, l;
        h.x = f2bf(v.x); l.x = f2bf(v.x - bf2f(h.x));
        h.y = f2bf(v.y); l.y = f2bf(v.y - bf2f(h.y));
        h.z = f2bf(v.z); l.z = f2bf(v.z - bf2f(h.z));
        h.w = f2bf(v.w); l.w = f2bf(v.w - bf2f(h.w));
        *(ushort4*)(Ah + r * 264 + q * 4) = h;
        *(ushort4*)(Al + r * 264 + q * 4) = l;
    }
    __syncthreads();

    f32x4 acc0 = (f32x4){0.f, 0.f, 0.f, 0.f};
    f32x4 acc1 = (f32x4){0.f, 0.f, 0.f, 0.f};
    int ct0 = 2 * w, ct1 = 2 * w + 1;

#pragma unroll 2
    for (int ks = 0; ks < 8; ks++) {
        bf16x8 ahi = *(bf16x8*)(Ah + lr * 264 + ks * 32 + kg * 8);
        bf16x8 alo = *(bf16x8*)(Al + lr * 264 + ks * 32 + kg * 8);
        size_t o0 = (size_t)((ct0 * 8 + ks) * 64 + lane) * 8;
        size_t o1 = (size_t)((ct1 * 8 + ks) * 64 + lane) * 8;
        bf16x8 bh0 = *(const bf16x8*)(Bphi + o0);
        bf16x8 bl0 = *(const bf16x8*)(Bplo + o0);
        bf16x8 bh1 = *(const bf16x8*)(Bphi + o1);
        bf16x8 bl1 = *(const bf16x8*)(Bplo + o1);
        acc0 = __builtin_amdgcn_mfma_f32_16x16x32_bf16(ahi, bh0, acc0, 0, 0, 0);
        acc0 = __builtin_amdgcn_mfma_f32_16x16x32_bf16(ahi, bl0, acc0, 0, 0, 0);
        acc0 = __builtin_amdgcn_mfma_f32_16x16x32_bf16(alo, bh0, acc0, 0, 0, 0);
        acc1 = __builtin_amdgcn_mfma_f32_16x16x32_bf16(ahi, bh1, acc1, 0, 0, 0);
        acc1 = __builtin_amdgcn_mfma_f32_16x16x32_bf16(ahi, bl1, acc1, 0, 0, 0);
        acc1 = __builtin_amdgcn_mfma_f32_16x16x32_bf16(alo, bh1, acc1, 0, 0, 0);
    }

#pragma unroll
    for (int r = 0; r < 4; r++) {
        int row = row0 + kg * 4 + r;            // D: row=(lane>>4)*4+reg [m89-verified]
        int c0 = ct0 * 16 + lr, c1 = ct1 * 16 + lr;
        float v0 = acc0[r], v1 = acc1[r];
        WhB[(size_t)row * DDIM + c0] = f2bf(v0);
        WhB[(size_t)row * DDIM + c1] = f2bf(v1);
        float q1 = v0 * a[c0] + v1 * a[c1];
        float q2 = v0 * a[DDIM + c0] + v1 * a[DDIM + c1];
        for (int o = 1; o < 16; o <<= 1) {
            q1 += __shfl_xor(q1, o, 16);
            q2 += __shfl_xor(q2, o, 16);
        }
        if (lr == 0) { ps1[w * 16 + kg * 4 + r] = q1; ps2[w * 16 + kg * 4 + r] = q2; }
    }
    __syncthreads();
    if (t < 16) {
        s1[row0 + t] = (ps1[t] + ps1[16 + t]) + (ps1[32 + t] + ps1[48 + t]);
        s2[row0 + t] = (ps2[t] + ps2[16 + t]) + (ps2[32 + t] + ps2[48 + t]);
    }
}

// ---------------- wave-per-row: merge 8 replica lists + dedup + softmax + gather ----
// Wave-private LDS bitmap dedup + append (R17-validated pattern); per replica k,
// lanes < deg_k read the 128B sub-list coalesced. Then exp/sum/gather as R12-R18.
__global__ __launch_bounds__(256) void row_wave_k(const unsigned* __restrict__ cnt8,
                                                  const unsigned* __restrict__ ell8,
                                                  const float* __restrict__ s1v,
                                                  const float* __restrict__ s2v,
                                                  const unsigned short* __restrict__ WhB,
                                                  float* __restrict__ out) {
    __shared__ unsigned bmw[4][256];   // per-wave dedup bitmap (1KB each)
    __shared__ float    pe[4][MAXD];
    __shared__ unsigned jl[4][MAXD];
    __shared__ unsigned lcnt[4];

    int w = threadIdx.x >> 6, lane = threadIdx.x & 63;
    int i = blockIdx.x * 4 + w;
    const ushort2* WhB2 = (const ushort2*)WhB;

    ((uint4*)bmw[w])[lane] = make_uint4(0u, 0u, 0u, 0u);
    if (lane == 0) lcnt[w] = 0u;       // wave-private; DS unit is in-order per wave
    float s1i = s1v[i];
    float lmax = -3e38f;

#pragma unroll
    for (int k = 0; k < NREP; k++) {
        size_t rowk = (size_t)k * N_NODES + i;
        unsigned dk = cnt8[rowk];      // wave-uniform scalar load
        if (dk > RSL) dk = RSL;
        if (lane < (int)dk) {
            unsigned j = ell8[rowk * RSL + lane];
            unsigned m = 1u << (j & 31);
            unsigned old = atomicOr(&bmw[w][j >> 5], m);
            if (!(old & m)) {
                float e = s1i + s2v[j];
                e = e > 0.f ? e : SLOPE * e;
                lmax = fmaxf(lmax, e);
                unsigned pos = atomicAdd(&lcnt[w], 1u);
                if (pos < MAXD) { jl[w][pos] = j; pe[w][pos] = e; }
            }
        }
    }
    for (int o = 32; o; o >>= 1) lmax = fmaxf(lmax, __shfl_xor(lmax, o, 64));
    unsigned deg = lcnt[w];            // all wave DS ops precede (in-order DS)
    if (deg > MAXD) deg = MAXD;

    if (deg == 0u) {
        // all-masked row -> uniform softmax -> elu(mean(Wh)); never taken on this input
        float sx = 0.f, sy = 0.f;
        for (int rr = 0; rr < N_NODES; rr++) {
            ushort2 u = WhB2[(size_t)rr * 64 + lane];
            sx += bf2f(u.x); sy += bf2f(u.y);
        }
        sx *= (1.0f / N_NODES); sy *= (1.0f / N_NODES);
        sx = sx > 0.f ? sx : __expf(sx) - 1.f;
        sy = sy > 0.f ? sy : __expf(sy) - 1.f;
        ((float2*)out)[(size_t)i * 64 + lane] = make_float2(sx, sy);
        return;
    }

    // exp in-place + wave sum (deterministic: fixed lane partition of [0,deg))
    float lsum = 0.f;
    for (unsigned n = lane; n < deg; n += 64) {
        float p = __expf(pe[w][n] - lmax);
        pe[w][n] = p;
        lsum += p;
    }
    for (int o = 32; o; o >>= 1) lsum += __shfl_xor(lsum, o, 64);
    float inv = 1.0f / lsum;

    // gather: one 256B bf16 Wh row per neighbor, fp32 accumulate
    float ax = 0.f, ay = 0.f;
#pragma unroll 8
    for (unsigned n = 0; n < deg; ++n) {
        float p = pe[w][n];            // LDS broadcast
        unsigned j = jl[w][n];
        ushort2 u = WhB2[(size_t)j * 64 + lane];
        ax = fmaf(p, bf2f(u.x), ax);
        ay = fmaf(p, bf2f(u.y), ay);
    }
    ax *= inv; ay *= inv;
    ax = ax > 0.f ? ax : __expf(ax) - 1.f;
    ay = ay > 0.f ? ay : __expf(ay) - 1.f;
    ((float2*)out)[(size_t)i * 64 + lane] = make_float2(ax, ay);
}

extern "C" void kernel_launch(void* const* d_in, const int* in_sizes, int n_in,
                              void* d_out, int out_size, void* d_ws, size_t ws_size,
                              hipStream_t stream) {
    const int*   edge = (const int*)d_in[0];    // [2, E] int32
    const float* X    = (const float*)d_in[1];  // [N, F]
    const float* Ws   = (const float*)d_in[2];  // [F, D]
    const float* a    = (const float*)d_in[3];  // [2D, 1]
    float*       out  = (float*)d_out;          // [N, D]
    int E = in_sizes[0] / 2;

    char* ws = (char*)d_ws;
    size_t off = 0;
    unsigned*       cnt8 = (unsigned*)(ws + off); off += (size_t)NREP * N_NODES * 4;        // 256 KB
    unsigned*       ell8 = (unsigned*)(ws + off); off += (size_t)NREP * N_NODES * RSL * 4;  // 8 MB
    float*          s1   = (float*)(ws + off);    off += N_NODES * 4;                       // 32 KB
    float*          s2   = (float*)(ws + off);    off += N_NODES * 4;                       // 32 KB
    unsigned short* WhB  = (unsigned short*)(ws + off); off += (size_t)N_NODES * DDIM * 2;  // 2 MB
    unsigned short* Bphi = (unsigned short*)(ws + off); off += (size_t)FDIM * DDIM * 2;     // 64 KB
    unsigned short* Bplo = (unsigned short*)(ws + off); off += (size_t)FDIM * DDIM * 2;     // 64 KB

    int nbuild = (E + 255) / 256;   // 1024
    prep_k<<<256, 256, 0, stream>>>(Ws, Bphi, Bplo, cnt8);
    mega_k<<<512 + nbuild, 256, 0, stream>>>(edge, E, X, Bphi, Bplo, a, WhB, s1, s2, cnt8, ell8);
    row_wave_k<<<N_NODES / 4, 256, 0, stream>>>(cnt8, ell8, s1, s2, WhB, out);
}